// Round 3
// baseline (3590.091 us; speedup 1.0000x reference)
//
#include <hip/hip_runtime.h>
#include <hip/hip_fp16.h>
#include <hip/hip_cooperative_groups.h>
#include <math.h>

namespace cg = cooperative_groups;

// Problem constants (fixed by the reference)
#define N      4096          // N_HID == N_TH == N_TP
#define KSTEPS 8
#define NF     16384         // feature length for W3
#define NB     256           // blocks (1 per CU)
#define NT     1024          // threads per block (16 waves)

// ---------------------------------------------------------------------------
// fp32 -> fp16 conversion. One thread = 8 elements.
// ---------------------------------------------------------------------------
__global__ void cvt_kernel(const float* __restrict__ src,
                           __half* __restrict__ dst) {
    size_t idx = (size_t)blockIdx.x * blockDim.x + threadIdx.x;
    const float4* s4 = (const float4*)src;
    float4 a = s4[2 * idx];
    float4 b = s4[2 * idx + 1];
    union { float4 f; __half2 h[4]; } u;
    u.h[0] = __floats2half2_rn(a.x, a.y);
    u.h[1] = __floats2half2_rn(a.z, a.w);
    u.h[2] = __floats2half2_rn(b.x, b.y);
    u.h[3] = __floats2half2_rn(b.z, b.w);
    ((float4*)dst)[idx] = u.f;
}

// ---------------------------------------------------------------------------
// wave / block reductions
// ---------------------------------------------------------------------------
__device__ inline float wred_sum(float v) {
    #pragma unroll
    for (int o = 32; o > 0; o >>= 1) v += __shfl_down(v, o);
    return v;
}
__device__ inline float wred_max(float v) {
    #pragma unroll
    for (int o = 32; o > 0; o >>= 1) v = fmaxf(v, __shfl_down(v, o));
    return v;
}
// all NT threads must call; sm needs >=17 floats
__device__ inline float block_red(float v, float* sm, bool ismax) {
    int tid = threadIdx.x, lane = tid & 63, wv = tid >> 6;
    __syncthreads();                       // protect sm reuse
    v = ismax ? wred_max(v) : wred_sum(v);
    if (lane == 0) sm[wv] = v;
    __syncthreads();
    if (tid == 0) {
        float r = sm[0];
        for (int i = 1; i < 16; ++i) r = ismax ? fmaxf(r, sm[i]) : r + sm[i];
        sm[16] = r;
    }
    __syncthreads();
    return sm[16];
}

// dot of 8 fp16 weights (in a float4) with 8 fp32 activations at chunk c
__device__ inline float dot8(float4 wf, const float4* __restrict__ x, int c) {
    union { float4 f; __half2 h2[4]; } u;
    u.f = wf;
    float4 x0 = x[2 * c], x1 = x[2 * c + 1];
    float2 p0 = __half22float2(u.h2[0]), p1 = __half22float2(u.h2[1]);
    float2 p2 = __half22float2(u.h2[2]), p3 = __half22float2(u.h2[3]);
    return p0.x * x0.x + p0.y * x0.y + p1.x * x0.z + p1.y * x0.w
         + p2.x * x1.x + p2.y * x1.y + p3.x * x1.z + p3.y * x1.w;
}

// ---------------------------------------------------------------------------
// Persistent cooperative kernel: entire pipeline after the fp16 conversions.
// 256 blocks x 1024 threads, 4 grid syncs per iteration.
// ---------------------------------------------------------------------------
__global__ void __launch_bounds__(NT, 1)
mega_kernel(const float* __restrict__ M_h,
            const __half* __restrict__ W2h,
            const __half* __restrict__ M_ph,
            const float* __restrict__ w1,
            const float* __restrict__ W3,
            const __half* __restrict__ wih,
            const __half* __restrict__ whh,
            float* __restrict__ v,
            float* __restrict__ u,
            float* __restrict__ sk_a,
            float* __restrict__ sk_b,
            float* __restrict__ xk_a,
            float* __restrict__ xk_b,
            float* __restrict__ out) {
    cg::grid_group grid = cg::this_grid();
    __shared__ float sm[32];
    __shared__ float wrow[16];

    int tid = threadIdx.x, bid = blockIdx.x;
    int lane = tid & 63, wv = tid >> 6;
    int i0 = bid * 16;                    // this block's 16-row slice

    float Pr0 = 0.f, Pr1 = 0.f, Pr2 = 0.f;   // live only in block0/tid0

    // ---- P0a: v[c] = sum_i w1[i] * M_h[i][c]  (fp32; v pre-zeroed) --------
    {
        float a0 = 0.f, a1 = 0.f, a2 = 0.f, a3 = 0.f;
        for (int i = 0; i < 16; ++i) {
            float wi = w1[i0 + i];
            float4 m = ((const float4*)(M_h + (size_t)(i0 + i) * N))[tid];
            a0 += wi * m.x; a1 += wi * m.y; a2 += wi * m.z; a3 += wi * m.w;
        }
        atomicAdd(&v[tid * 4 + 0], a0);
        atomicAdd(&v[tid * 4 + 1], a1);
        atomicAdd(&v[tid * 4 + 2], a2);
        atomicAdd(&v[tid * 4 + 3], a3);
    }
    grid.sync();

    // ---- P0b: alpha = softmax(v) (redundant per block); sk0 = alpha @ M_h -
    {
        float m = -1e30f;
        for (int i = tid; i < N; i += NT) m = fmaxf(m, v[i]);
        m = block_red(m, sm, true);
        float s = 0.f;
        for (int i = tid; i < N; i += NT) s += expf(v[i] - m);
        s = block_red(s, sm, false);
        float inv = 1.f / s;
        if (tid < 16) wrow[tid] = expf(v[i0 + tid] - m) * inv;
        __syncthreads();
        float a0 = 0.f, a1 = 0.f, a2 = 0.f, a3 = 0.f;
        for (int i = 0; i < 16; ++i) {
            float wi = wrow[i];
            float4 mm = ((const float4*)(M_h + (size_t)(i0 + i) * N))[tid];
            a0 += wi * mm.x; a1 += wi * mm.y; a2 += wi * mm.z; a3 += wi * mm.w;
        }
        atomicAdd(&sk_a[tid * 4 + 0], a0);
        atomicAdd(&sk_a[tid * 4 + 1], a1);
        atomicAdd(&sk_a[tid * 4 + 2], a2);
        atomicAdd(&sk_a[tid * 4 + 3], a3);
    }
    grid.sync();

    float* h  = sk_a;
    float* hn = sk_b;
    for (int k = 0; k < KSTEPS; ++k) {
        float* xk = (k & 1) ? xk_b : xk_a;

        // ---- P1: u = W2h @ h (one row per wave); zero v for P2 ----------
        if (tid < 16) v[i0 + tid] = 0.f;
        {
            int row = bid * 16 + wv;
            const float4* r = (const float4*)(W2h + (size_t)row * N);
            const float4* x = (const float4*)h;
            float acc = 0.f;
            #pragma unroll
            for (int j = 0; j < 8; ++j) {
                int c = lane + 64 * j;
                acc += dot8(r[c], x, c);
            }
            acc = wred_sum(acc);
            if (lane == 0) u[row] = acc;
        }
        grid.sync();

        // ---- P2: v[c] += sum_i u[i] * M_ph[i][c]; zero xk ---------------
        if (tid < 16) xk[i0 + tid] = 0.f;
        if (tid < 16) wrow[tid] = u[i0 + tid];
        __syncthreads();
        {
            float a0 = 0.f, a1 = 0.f, a2 = 0.f, a3 = 0.f;
            for (int i = 0; i < 16; ++i) {
                float wi = wrow[i];
                union { float2 f; __half2 h2[2]; } mu;
                mu.f = ((const float2*)(M_ph + (size_t)(i0 + i) * N))[tid];
                float2 p0 = __half22float2(mu.h2[0]);
                float2 p1 = __half22float2(mu.h2[1]);
                a0 += wi * p0.x; a1 += wi * p0.y;
                a2 += wi * p1.x; a3 += wi * p1.y;
            }
            atomicAdd(&v[tid * 4 + 0], a0);
            atomicAdd(&v[tid * 4 + 1], a1);
            atomicAdd(&v[tid * 4 + 2], a2);
            atomicAdd(&v[tid * 4 + 3], a3);
        }
        grid.sync();

        // ---- P3/4: beta = softmax(v) (redundant); xk = beta @ M_ph ------
        {
            float m = -1e30f;
            for (int i = tid; i < N; i += NT) m = fmaxf(m, v[i]);
            m = block_red(m, sm, true);
            float s = 0.f;
            for (int i = tid; i < N; i += NT) s += expf(v[i] - m);
            s = block_red(s, sm, false);
            float inv = 1.f / s;
            if (tid < 16) wrow[tid] = expf(v[i0 + tid] - m) * inv;
            __syncthreads();
            float a0 = 0.f, a1 = 0.f, a2 = 0.f, a3 = 0.f;
            for (int i = 0; i < 16; ++i) {
                float wi = wrow[i];
                union { float2 f; __half2 h2[2]; } mu;
                mu.f = ((const float2*)(M_ph + (size_t)(i0 + i) * N))[tid];
                float2 p0 = __half22float2(mu.h2[0]);
                float2 p1 = __half22float2(mu.h2[1]);
                a0 += wi * p0.x; a1 += wi * p0.y;
                a2 += wi * p1.x; a3 += wi * p1.y;
            }
            atomicAdd(&xk[tid * 4 + 0], a0);
            atomicAdd(&xk[tid * 4 + 1], a1);
            atomicAdd(&xk[tid * 4 + 2], a2);
            atomicAdd(&xk[tid * 4 + 3], a3);
        }
        grid.sync();

        // ---- P5: GRU cell, one hidden unit per wave ---------------------
        {
            int t = bid * 16 + wv;
            float ai0 = 0.f, ai1 = 0.f, ai2 = 0.f;
            float ah0 = 0.f, ah1 = 0.f, ah2 = 0.f;
            const float4* xv = (const float4*)xk;
            const float4* hv = (const float4*)h;
            const float4* wi0 = (const float4*)(wih + (size_t)(0 * N + t) * N);
            const float4* wi1 = (const float4*)(wih + (size_t)(1 * N + t) * N);
            const float4* wi2 = (const float4*)(wih + (size_t)(2 * N + t) * N);
            const float4* wh0 = (const float4*)(whh + (size_t)(0 * N + t) * N);
            const float4* wh1 = (const float4*)(whh + (size_t)(1 * N + t) * N);
            const float4* wh2 = (const float4*)(whh + (size_t)(2 * N + t) * N);
            #pragma unroll
            for (int j = 0; j < 8; ++j) {
                int c = lane + 64 * j;
                ai0 += dot8(wi0[c], xv, c);
                ai1 += dot8(wi1[c], xv, c);
                ai2 += dot8(wi2[c], xv, c);
                ah0 += dot8(wh0[c], hv, c);
                ah1 += dot8(wh1[c], hv, c);
                ah2 += dot8(wh2[c], hv, c);
            }
            ai0 = wred_sum(ai0); ai1 = wred_sum(ai1); ai2 = wred_sum(ai2);
            ah0 = wred_sum(ah0); ah1 = wred_sum(ah1); ah2 = wred_sum(ah2);
            if (lane == 0) {
                float r = 1.f / (1.f + expf(-(ai0 + ah0)));
                float z = 1.f / (1.f + expf(-(ai1 + ah1)));
                float n = tanhf(ai2 + r * ah2);
                hn[t] = (1.f - z) * n + z * h[t];
            }
        }
        grid.sync();

        // ---- P6 (block 0 only, overlaps next P1): label head ------------
        if (bid == 0) {
            float a0 = 0.f, a1 = 0.f, a2 = 0.f;
            for (int f = tid; f < NF; f += NT) {
                int j = f & (N - 1);
                int seg = f >> 12;
                float sv = hn[j], xv2 = xk[j];
                float val;
                if (seg == 0)      val = sv;
                else if (seg == 1) val = xv2;
                else if (seg == 2) val = fabsf(sv - xv2);
                else               val = sv * xv2;
                a0 += val * W3[f * 3 + 0];
                a1 += val * W3[f * 3 + 1];
                a2 += val * W3[f * 3 + 2];
            }
            a0 = block_red(a0, sm, false);
            a1 = block_red(a1, sm, false);
            a2 = block_red(a2, sm, false);
            if (tid == 0) {
                float m = fmaxf(a0, fmaxf(a1, a2));
                float e0 = expf(a0 - m), e1 = expf(a1 - m), e2 = expf(a2 - m);
                float ssum = e0 + e1 + e2;
                Pr0 += e0 / ssum; Pr1 += e1 / ssum; Pr2 += e2 / ssum;
                if (k == KSTEPS - 1) {
                    out[0] = Pr0 / (float)KSTEPS;
                    out[1] = Pr1 / (float)KSTEPS;
                    out[2] = Pr2 / (float)KSTEPS;
                }
            }
        }
        float* tptr = h; h = hn; hn = tptr;
    }
}

extern "C" void kernel_launch(void* const* d_in, const int* in_sizes, int n_in,
                              void* d_out, int out_size, void* d_ws, size_t ws_size,
                              hipStream_t stream) {
    const float* M_h  = (const float*)d_in[0];
    const float* M_p  = (const float*)d_in[1];
    const float* w1   = (const float*)d_in[2];
    const float* W2   = (const float*)d_in[3];
    const float* W3   = (const float*)d_in[4];
    const float* w_ih = (const float*)d_in[5];
    const float* w_hh = (const float*)d_in[6];
    float* out = (float*)d_out;

    // ---- workspace layout -------------------------------------------------
    char* base = (char*)d_ws;
    const size_t SZ_NN  = (size_t)N * N * sizeof(__half);        // 32 MiB
    const size_t SZ_3NN = (size_t)3 * N * N * sizeof(__half);    // 96 MiB
    __half* W2h  = (__half*)(base);
    __half* M_ph = (__half*)(base + SZ_NN);
    __half* wihh = (__half*)(base + 2 * SZ_NN);
    __half* whhh = (__half*)(base + 2 * SZ_NN + SZ_3NN);
    float*  fs   = (float*)(base + 2 * SZ_NN + 2 * SZ_3NN);
    float* v    = fs;             // 4096
    float* u    = fs + 4096;      // 4096
    float* sk_a = fs + 8192;      // 4096
    float* sk_b = fs + 12288;     // 4096
    float* xk_a = fs + 16384;     // 4096
    float* xk_b = fs + 20480;     // 4096

    // zero small scratch (d_ws is poisoned to 0xAA before each call)
    hipMemsetAsync(fs, 0, (size_t)24576 * sizeof(float), stream);

    // fp16 conversions (independent, full-grid, no syncs needed)
    cvt_kernel<<<(N / 8) * (N / 256), 256, 0, stream>>>(W2,   W2h);
    cvt_kernel<<<(N / 8) * (N / 256), 256, 0, stream>>>(M_p,  M_ph);
    cvt_kernel<<<3 * (N / 8) * (N / 256), 256, 0, stream>>>(w_ih, wihh);
    cvt_kernel<<<3 * (N / 8) * (N / 256), 256, 0, stream>>>(w_hh, whhh);

    // one persistent cooperative kernel for everything else
    void* kargs[] = {
        (void*)&M_h, (void*)&W2h, (void*)&M_ph, (void*)&w1, (void*)&W3,
        (void*)&wihh, (void*)&whhh,
        (void*)&v, (void*)&u, (void*)&sk_a, (void*)&sk_b,
        (void*)&xk_a, (void*)&xk_b, (void*)&out
    };
    hipLaunchCooperativeKernel((void*)mega_kernel, dim3(NB), dim3(NT),
                               kargs, 0, stream);
}